// Round 10
// baseline (186.316 us; speedup 1.0000x reference)
//
#include <hip/hip_runtime.h>
#include <hip/hip_bf16.h>
#include <math.h>

typedef __bf16 bf16;
typedef bf16 bf16x8 __attribute__((ext_vector_type(8)));
typedef bf16 bf16x4 __attribute__((ext_vector_type(4)));
typedef float f32x4 __attribute__((ext_vector_type(4)));

#define N_NODES 8192
#define DIN 256
#define DOUT 256
#define KCAT 512
#define EPSF 1e-8f
#define KSPLIT 8
#define KBLK 1024          // K per k2 block
#define BM 128
#define BK 64
#define NT (KBLK / BK)     // 16 tiles

__device__ __forceinline__ f32x4 mfma16(bf16x8 a, bf16x8 b, f32x4 c) {
    return __builtin_amdgcn_mfma_f32_16x16x32_bf16(a, b, c, 0, 0, 0);
}

#define WAITVM(N) asm volatile("s_waitcnt vmcnt(" #N ")" ::: "memory")
#define WAITLGKM  asm volatile("s_waitcnt lgkmcnt(0)" ::: "memory")
#define BAR       __builtin_amdgcn_s_barrier()

// ---------------- K0: W_w [256x256] -> WwT[n][k] bf16 ; W_fc [512x256] -> WfcT[n][k] bf16
__global__ __launch_bounds__(256) void k0_prep(const float* __restrict__ Ww,
                                               const float* __restrict__ Wfc,
                                               bf16* __restrict__ WwT,
                                               bf16* __restrict__ WfcT) {
    int tid = blockIdx.x * 256 + threadIdx.x;
    if (tid < 256 * 256) {
        int n = tid >> 8, k = tid & 255;
        WwT[n * 256 + k] = (bf16)Ww[k * 256 + n];
    }
    if (tid < 256 * 512) {
        int n = tid >> 9, k = tid & 511;
        WfcT[n * 512 + k] = (bf16)Wfc[k * 256 + n];
    }
}

// ---------------- K1: hT[col][m] = bf16(relu(X @ W_w + b_w))
__global__ __launch_bounds__(128) void k1_h(const float* __restrict__ X,
                                            const bf16* __restrict__ WwT,
                                            const float* __restrict__ bw,
                                            bf16* __restrict__ hT) {
    const int lane = threadIdx.x & 63;
    const int wid  = threadIdx.x >> 6;   // 0..1
    const int m0   = blockIdx.x * 16;
    const int lrow = lane & 15;
    const int lk8  = (lane >> 4) * 8;

    f32x4 acc[8];
#pragma unroll
    for (int i = 0; i < 8; ++i) acc[i] = {0.f, 0.f, 0.f, 0.f};

#pragma unroll
    for (int ks = 0; ks < DIN; ks += 32) {
        const float* xp = X + (size_t)(m0 + lrow) * DIN + ks + lk8;
        f32x4 x0 = *reinterpret_cast<const f32x4*>(xp);
        f32x4 x1 = *reinterpret_cast<const f32x4*>(xp + 4);
        bf16x8 a;
#pragma unroll
        for (int j = 0; j < 4; ++j) { a[j] = (bf16)x0[j]; a[4 + j] = (bf16)x1[j]; }
#pragma unroll
        for (int nb = 0; nb < 8; ++nb) {
            int col = wid * 128 + nb * 16 + lrow;
            bf16x8 b = *reinterpret_cast<const bf16x8*>(WwT + (size_t)col * DIN + ks + lk8);
            acc[nb] = mfma16(a, b, acc[nb]);
        }
    }
    const int mrow = m0 + (lane >> 4) * 4;
#pragma unroll
    for (int nb = 0; nb < 8; ++nb) {
        int col = wid * 128 + nb * 16 + lrow;
        float bias = bw[col];
        bf16x4 hv;
#pragma unroll
        for (int j = 0; j < 4; ++j) {
            float v = acc[nb][j] + bias;
            hv[j] = (bf16)(v > 0.f ? v : 0.f);
        }
        *reinterpret_cast<bf16x4*>(hT + (size_t)col * N_NODES + mrow) = hv;
    }
}

// ---------------- K2: part[ks] = A[m0:m0+128, kbase:+1024] @ h ; rsG[ks] = rowsum partial
// CLEAN TLP PROBE: R3's exact tile geometry (BM=128, BN=256, BK=64 — the only
// config family that hits 138 total) but TWO blocks co-resident per CU:
// LDS = B dbuf 2x32KB + A SINGLE 16KB = 80KB exactly -> 2 blocks/CU, two
// INDEPENDENT barrier/vmcnt chains so one block's latency stall hides under
// the other's compute (m114). Per-CU bytes/reuse byte-identical to R3.
// A single-buffer costs a 2nd barrier/iter; NT halved to 16 (KSPLIT=8) keeps
// total barrier count at R3's level. A-regs still double-buffer across BAR.
// vmcnt ladder (hand-simulated): steady invariant [B(t+1):4, A(t+1):4];
// CVTW's compiler-inserted vmcnt(4) retires exactly B(t+1)+A(t+1).
// Rowsum via fp32 VALU during staging + pair shfl (R7-verified).
__global__ __launch_bounds__(512, 4) void k2_pool(const float* __restrict__ A,
                                                  const bf16* __restrict__ hT,
                                                  float* __restrict__ part,
                                                  float* __restrict__ rsG) {
    __shared__ __align__(16) unsigned char ldsA[16384];      // [128 rows][128 B]
    __shared__ __align__(16) unsigned char ldsB[2][32768];   // [256 cols][128 B] x2
    const int t    = threadIdx.x;
    const int lane = t & 63;
    const int wid  = t >> 6;        // 0..7
    const int wr   = wid >> 2;      // 0..1  (row half)
    const int wn   = wid & 3;       // 0..3  (col quarter)
    const int lrow = lane & 15;
    const int lk4  = lane >> 4;     // 0..3
    const int mblk = blockIdx.x & 63;
    const int ks   = blockIdx.x >> 6;   // 0..7
    const int m0   = mblk * BM;
    const int kbase = ks * KBLK;

    f32x4 acc[4][4];
#pragma unroll
    for (int i = 0; i < 4; ++i)
#pragma unroll
        for (int j = 0; j < 4; ++j) acc[i][j] = {0.f, 0.f, 0.f, 0.f};

    float rsum = 0.f;

    // ---- A staging: thread t -> row t>>2, 16 floats at (t&3)*16
    const int arow = t >> 2;
    const int aq   = t & 3;
    const float* aSrc = A + (size_t)(m0 + arow) * N_NODES + kbase + aq * 16;
    const int awb0 = arow * 128 + (((aq * 2)     ^ (arow & 7)) << 4);
    const int awb1 = arow * 128 + (((aq * 2 + 1) ^ (arow & 7)) << 4);

    // ---- B DMA (4 rounds): idx = r*512+t -> col=idx>>3, seg=(idx&7)^(col&7)
    const bf16* bsrc[4];
    int bdst[4];
#pragma unroll
    for (int r = 0; r < 4; ++r) {
        int idx = r * 512 + t;
        int col = idx >> 3;
        int gs  = (idx & 7) ^ (col & 7);
        bsrc[r] = hT + (size_t)col * N_NODES + kbase + gs * 8;
        bdst[r] = (r * 8 + wid) * 1024;   // wave-uniform base within stage
    }

    // ---- fragment read byte offsets
    int aOff[2][4], bOff[2][4];
#pragma unroll
    for (int kki = 0; kki < 2; ++kki) {
        int sA = kki * 4 + lk4;
#pragma unroll
        for (int f = 0; f < 4; ++f) {
            int row = wr * 64 + f * 16 + lrow;
            aOff[kki][f] = row * 128 + ((sA ^ (row & 7)) << 4);
            int col = wn * 64 + f * 16 + lrow;
            bOff[kki][f] = col * 128 + ((sA ^ (col & 7)) << 4);
        }
    }

    f32x4 ra0, ra1, ra2, ra3;

#define ALOAD(tile) do {                                                      \
        const float* p_ = aSrc + (size_t)(tile) * BK;                         \
        ra0 = *reinterpret_cast<const f32x4*>(p_);                            \
        ra1 = *reinterpret_cast<const f32x4*>(p_ + 4);                        \
        ra2 = *reinterpret_cast<const f32x4*>(p_ + 8);                        \
        ra3 = *reinterpret_cast<const f32x4*>(p_ + 12);                       \
    } while (0)

#define CVTW() do {                                                           \
        bf16x8 w0_, w1_;                                                      \
        _Pragma("unroll")                                                     \
        for (int j_ = 0; j_ < 4; ++j_) {                                      \
            w0_[j_]     = (bf16)ra0[j_]; w0_[4 + j_] = (bf16)ra1[j_];         \
            w1_[j_]     = (bf16)ra2[j_]; w1_[4 + j_] = (bf16)ra3[j_];         \
            rsum += ra0[j_] + ra1[j_] + ra2[j_] + ra3[j_];                    \
        }                                                                     \
        *reinterpret_cast<bf16x8*>(&ldsA[awb0]) = w0_;                        \
        *reinterpret_cast<bf16x8*>(&ldsA[awb1]) = w1_;                        \
    } while (0)

#define BDMA(tile, st) do {                                                   \
        _Pragma("unroll")                                                     \
        for (int r_ = 0; r_ < 4; ++r_) {                                      \
            __builtin_amdgcn_global_load_lds(                                 \
                (const __attribute__((address_space(1))) void*)(bsrc[r_] + (size_t)(tile) * BK), \
                (__attribute__((address_space(3))) void*)&ldsB[st][bdst[r_]], \
                16, 0, 0);                                                    \
        }                                                                     \
    } while (0)

#define COMPUTE(st) do {                                                      \
        _Pragma("unroll")                                                     \
        for (int kki = 0; kki < 2; ++kki) {                                   \
            bf16x8 af_[4], bf_[4];                                            \
            _Pragma("unroll")                                                 \
            for (int f = 0; f < 4; ++f) {                                     \
                af_[f] = *reinterpret_cast<const bf16x8*>(&ldsA[aOff[kki][f]]); \
                bf_[f] = *reinterpret_cast<const bf16x8*>(&ldsB[st][bOff[kki][f]]); \
            }                                                                 \
            _Pragma("unroll")                                                 \
            for (int mf = 0; mf < 4; ++mf)                                    \
                _Pragma("unroll")                                             \
                for (int nf = 0; nf < 4; ++nf)                                \
                    acc[mf][nf] = mfma16(af_[mf], bf_[nf], acc[mf][nf]);      \
        }                                                                     \
    } while (0)

    // ---------------- prologue: queue -> [B0,B1] -> CVTW(A0) -> [B0,B1,A1] -> WAITVM(8)=[B1,A1]
    ALOAD(0);
    BDMA(0, 0);
    BDMA(1, 1);
    CVTW();                      // compiler waits A(0) precisely (vmcnt 8)
    ALOAD(1);
    WAITVM(8);                   // retire B(0); B(1)+A(1) stay in flight
    WAITLGKM;                    // A(0) ds_writes visible
    BAR;                         // tile 0 ready (A in ldsA, B in ldsB[0])

    // ---------------- main loop: tiles 0 .. NT-3
    for (int tt = 0; tt < NT - 2; ++tt) {
        COMPUTE(tt & 1);         // A_lds(tt) + B[tt&1]
        BAR;                     // all waves done reading ldsA and ldsB[tt&1]
        BDMA(tt + 2, tt & 1);    // refill freed B stage
        CVTW();                  // A(tt+1) regs -> ldsA; implicit vmcnt(4)
                                 //   retires B(tt+1)+A(tt+1) exactly
        ALOAD(tt + 2);
        WAITVM(8);               // no-op in steady state (documented invariant)
        WAITLGKM;                // A(tt+1) ds_writes visible
        BAR;                     // tile tt+1 ready
    }
    // ---------------- tail: tiles NT-2, NT-1
    COMPUTE((NT - 2) & 1);
    BAR;
    CVTW();                      // A(NT-1); implicit wait drains B(NT-1)+A(NT-1)
    WAITLGKM;
    BAR;
    COMPUTE((NT - 1) & 1);

    // ---------------- rowsum: reduce the 4 col-quarter partials per row
    rsum += __shfl_xor(rsum, 1);
    rsum += __shfl_xor(rsum, 2);
    if (aq == 0) rsG[(size_t)ks * N_NODES + m0 + arow] = rsum;

    // ---------------- store f32 partial tile
    float* pp = part + ((size_t)ks * N_NODES + m0) * DOUT;
#pragma unroll
    for (int mf = 0; mf < 4; ++mf)
#pragma unroll
        for (int nf = 0; nf < 4; ++nf) {
            int col = wn * 64 + nf * 16 + lrow;
#pragma unroll
            for (int j = 0; j < 4; ++j) {
                int row = wr * 64 + mf * 16 + lk4 * 4 + j;
                pp[(size_t)row * DOUT + col] = acc[mf][nf][j];
            }
        }
#undef ALOAD
#undef CVTW
#undef BDMA
#undef COMPUTE
}

// ---------------- K3: out = relu([X || pooled] @ W_fc + b_fc) + eps  (pooled formed
// on the fly from part/rsG — k2b merged in), + per-block sumsq partial
__global__ __launch_bounds__(128) void k3_out(const float* __restrict__ X,
                                              const float* __restrict__ part,
                                              const float* __restrict__ rsG,
                                              const bf16* __restrict__ WfcT,
                                              const float* __restrict__ bfc,
                                              float* __restrict__ out,
                                              float* __restrict__ partials) {
    const int lane = threadIdx.x & 63;
    const int wid  = threadIdx.x >> 6;
    const int m0   = blockIdx.x * 16;
    const int lrow = lane & 15;
    const int lk8  = (lane >> 4) * 8;

    f32x4 acc[8];
#pragma unroll
    for (int i = 0; i < 8; ++i) acc[i] = {0.f, 0.f, 0.f, 0.f};

    // per-lane row scale 1/(rowsum+eps) for row m0+lrow
    float rs = EPSF;
#pragma unroll
    for (int sp = 0; sp < KSPLIT; ++sp) rs += rsG[(size_t)sp * N_NODES + m0 + lrow];
    const float inv = 1.f / rs;

    // k in [0,256): A-operand from X (fp32 -> bf16)
#pragma unroll
    for (int ksx = 0; ksx < 256; ksx += 32) {
        const float* xp = X + (size_t)(m0 + lrow) * DIN + ksx + lk8;
        f32x4 x0 = *reinterpret_cast<const f32x4*>(xp);
        f32x4 x1 = *reinterpret_cast<const f32x4*>(xp + 4);
        bf16x8 a;
#pragma unroll
        for (int j = 0; j < 4; ++j) { a[j] = (bf16)x0[j]; a[4 + j] = (bf16)x1[j]; }
#pragma unroll
        for (int nb = 0; nb < 8; ++nb) {
            int col = wid * 128 + nb * 16 + lrow;
            bf16x8 b = *reinterpret_cast<const bf16x8*>(WfcT + (size_t)col * KCAT + ksx + lk8);
            acc[nb] = mfma16(a, b, acc[nb]);
        }
    }
    // k in [256,512): A-operand = pooled, formed from sum of part splits * inv
#pragma unroll
    for (int ksx = 256; ksx < 512; ksx += 32) {
        f32x4 s0 = {0.f, 0.f, 0.f, 0.f}, s1 = {0.f, 0.f, 0.f, 0.f};
#pragma unroll
        for (int sp = 0; sp < KSPLIT; ++sp) {
            const float* pp = part + ((size_t)sp * N_NODES + m0 + lrow) * DOUT + (ksx - 256) + lk8;
            f32x4 v0 = *reinterpret_cast<const f32x4*>(pp);
            f32x4 v1 = *reinterpret_cast<const f32x4*>(pp + 4);
#pragma unroll
            for (int j = 0; j < 4; ++j) { s0[j] += v0[j]; s1[j] += v1[j]; }
        }
        bf16x8 a;
#pragma unroll
        for (int j = 0; j < 4; ++j) { a[j] = (bf16)(s0[j] * inv); a[4 + j] = (bf16)(s1[j] * inv); }
#pragma unroll
        for (int nb = 0; nb < 8; ++nb) {
            int col = wid * 128 + nb * 16 + lrow;
            bf16x8 b = *reinterpret_cast<const bf16x8*>(WfcT + (size_t)col * KCAT + ksx + lk8);
            acc[nb] = mfma16(a, b, acc[nb]);
        }
    }

    float ss = 0.f;
#pragma unroll
    for (int nb = 0; nb < 8; ++nb) {
        int col = wid * 128 + nb * 16 + lrow;
        float bias = bfc[col];
#pragma unroll
        for (int j = 0; j < 4; ++j) {
            int row = m0 + (lane >> 4) * 4 + j;
            float v = acc[nb][j] + bias;
            v = (v > 0.f ? v : 0.f) + EPSF;
            out[(size_t)row * DOUT + col] = v;
            ss += v * v;
        }
    }
#pragma unroll
    for (int off = 32; off; off >>= 1) ss += __shfl_xor(ss, off);
    __shared__ float sw[2];
    if (lane == 0) sw[wid] = ss;
    __syncthreads();
    if (threadIdx.x == 0) partials[blockIdx.x] = sw[0] + sw[1];
}

// ---------------- K4: deterministic reduce of 512 partials; scale out by 1/(norm+eps)
__global__ __launch_bounds__(256) void k4_norm(float* __restrict__ out,
                                               const float* __restrict__ partials) {
    __shared__ float sw[4];
    float s = partials[threadIdx.x] + partials[threadIdx.x + 256];
#pragma unroll
    for (int off = 32; off; off >>= 1) s += __shfl_xor(s, off);
    if ((threadIdx.x & 63) == 0) sw[threadIdx.x >> 6] = s;
    __syncthreads();
    float total = sw[0] + sw[1] + sw[2] + sw[3];
    float scale = 1.f / (sqrtf(total) + EPSF);
    f32x4* o4 = reinterpret_cast<f32x4*>(out);
    const int nvec = N_NODES * DOUT / 4;
    for (int i = blockIdx.x * blockDim.x + threadIdx.x; i < nvec; i += gridDim.x * blockDim.x) {
        f32x4 v = o4[i];
#pragma unroll
        for (int j = 0; j < 4; ++j) v[j] *= scale;
        o4[i] = v;
    }
}

extern "C" void kernel_launch(void* const* d_in, const int* in_sizes, int n_in,
                              void* d_out, int out_size, void* d_ws, size_t ws_size,
                              hipStream_t stream) {
    const float* A   = (const float*)d_in[0];
    const float* X   = (const float*)d_in[1];
    const float* Ww  = (const float*)d_in[2];
    const float* bw  = (const float*)d_in[3];
    const float* Wfc = (const float*)d_in[4];
    const float* bfc = (const float*)d_in[5];
    float* out = (float*)d_out;

    char* ws = (char*)d_ws;
    bf16*  hT        = (bf16*)(ws);                                  // 4 MiB
    bf16*  WwT       = (bf16*)(ws + (8u << 20));                     // 128 KiB
    bf16*  WfcT      = (bf16*)(ws + (8u << 20) + (128u << 10));      // 256 KiB
    float* partials  = (float*)(ws + (8u << 20) + (384u << 10));     // 2 KiB
    float* rsG       = (float*)(ws + (8u << 20) + (512u << 10));     // 256 KiB (8 splits)
    float* part      = (float*)(ws + (16u << 20));                   // 64 MiB (8 splits)

    k0_prep<<<512, 256, 0, stream>>>(Ww, Wfc, WwT, WfcT);
    k1_h<<<512, 128, 0, stream>>>(X, WwT, bw, hT);
    k2_pool<<<512, 512, 0, stream>>>(A, hT, part, rsG);
    k3_out<<<512, 128, 0, stream>>>(X, part, rsG, WfcT, bfc, out, partials);
    k4_norm<<<256, 256, 0, stream>>>(out, partials);
}

// Round 11
// 151.984 us; speedup vs baseline: 1.2259x; 1.2259x over previous
//
#include <hip/hip_runtime.h>
#include <hip/hip_bf16.h>
#include <math.h>

typedef __bf16 bf16;
typedef bf16 bf16x8 __attribute__((ext_vector_type(8)));
typedef bf16 bf16x4 __attribute__((ext_vector_type(4)));
typedef float f32x4 __attribute__((ext_vector_type(4)));

#define N_NODES 8192
#define DIN 256
#define DOUT 256
#define KCAT 512
#define EPSF 1e-8f
#define BM 32
#define BK 128
#define NT (N_NODES / BK)   // 64 tiles, full K per block (KSPLIT=1)
#define BB 16384            // B region base (A: 2 stages x 8 KB)
#define BSTG 65536          // B stage size (256 cols x 256 B)

__device__ __forceinline__ f32x4 mfma16(bf16x8 a, bf16x8 b, f32x4 c) {
    return __builtin_amdgcn_mfma_f32_16x16x32_bf16(a, b, c, 0, 0, 0);
}

#define WAITVM(N) asm volatile("s_waitcnt vmcnt(" #N ")" ::: "memory")
#define WAITLGKM  asm volatile("s_waitcnt lgkmcnt(0)" ::: "memory")
#define BAR       __builtin_amdgcn_s_barrier()

// ---------------- K0: W_w [256x256] -> WwT[n][k] bf16 ; W_fc [512x256] -> WfcT[n][k] bf16
__global__ __launch_bounds__(256) void k0_prep(const float* __restrict__ Ww,
                                               const float* __restrict__ Wfc,
                                               bf16* __restrict__ WwT,
                                               bf16* __restrict__ WfcT) {
    int tid = blockIdx.x * 256 + threadIdx.x;
    if (tid < 256 * 256) {
        int n = tid >> 8, k = tid & 255;
        WwT[n * 256 + k] = (bf16)Ww[k * 256 + n];
    }
    if (tid < 256 * 512) {
        int n = tid >> 9, k = tid & 511;
        WfcT[n * 512 + k] = (bf16)Wfc[k * 256 + n];
    }
}

// ---------------- K1: hT[col][m] = bf16(relu(X @ W_w + b_w))
__global__ __launch_bounds__(128) void k1_h(const float* __restrict__ X,
                                            const bf16* __restrict__ WwT,
                                            const float* __restrict__ bw,
                                            bf16* __restrict__ hT) {
    const int lane = threadIdx.x & 63;
    const int wid  = threadIdx.x >> 6;   // 0..1
    const int m0   = blockIdx.x * 16;
    const int lrow = lane & 15;
    const int lk8  = (lane >> 4) * 8;

    f32x4 acc[8];
#pragma unroll
    for (int i = 0; i < 8; ++i) acc[i] = {0.f, 0.f, 0.f, 0.f};

#pragma unroll
    for (int ks = 0; ks < DIN; ks += 32) {
        const float* xp = X + (size_t)(m0 + lrow) * DIN + ks + lk8;
        f32x4 x0 = *reinterpret_cast<const f32x4*>(xp);
        f32x4 x1 = *reinterpret_cast<const f32x4*>(xp + 4);
        bf16x8 a;
#pragma unroll
        for (int j = 0; j < 4; ++j) { a[j] = (bf16)x0[j]; a[4 + j] = (bf16)x1[j]; }
#pragma unroll
        for (int nb = 0; nb < 8; ++nb) {
            int col = wid * 128 + nb * 16 + lrow;
            bf16x8 b = *reinterpret_cast<const bf16x8*>(WwT + (size_t)col * DIN + ks + lk8);
            acc[nb] = mfma16(a, b, acc[nb]);
        }
    }
    const int mrow = m0 + (lane >> 4) * 4;
#pragma unroll
    for (int nb = 0; nb < 8; ++nb) {
        int col = wid * 128 + nb * 16 + lrow;
        float bias = bw[col];
        bf16x4 hv;
#pragma unroll
        for (int j = 0; j < 4; ++j) {
            float v = acc[nb][j] + bias;
            hv[j] = (bf16)(v > 0.f ? v : 0.f);
        }
        *reinterpret_cast<bf16x4*>(hT + (size_t)col * N_NODES + mrow) = hv;
    }
}

// ---------------- K2: pooled = (A @ h) / (rowsum(A)+eps), bf16 out — KSPLIT=1
// DRAM-STREAM PROBE: one block owns 32 FULL rows of A (BM=32, BK=128, NT=64,
// grid=256). Each A-row is ONE strictly sequential stream (8192 streams
// ~8/channel -> DRAM open-page friendly) instead of 4-8 interleaved k-phase
// pointers per row (~256 streams/channel) as in all KSPLIT>=4 configs — the
// last untested invariant behind the ~3.6 TB/s pattern ceiling.
// B = ALL of hT, streamed per-tile from L2/L3 via global_load_lds (64 KB/tile,
// source-pre-swizzled, linear dest). A: coalesced f32x4 -> cvt -> swizzled
// ds_write (8 KB/tile). Both dbuf; R3's proven 1-barrier counted-vmcnt ladder
// re-traced for (2 A-loads + 8 B-DMAs)/tile: steady WAITVM(2) retires B(t+1),
// leaves A(t+2). Swizzle: 256 B row pitch, phys_seg = seg ^ (row&15) (2-way
// bank aliasing only = free). Rowsum fused into staging VALU + 4 shfl —
// k2 writes pooled bf16 DIRECTLY (no part/rsG buffers at all).
__global__ __launch_bounds__(512) void k2_pool(const float* __restrict__ A,
                                               const bf16* __restrict__ hT,
                                               bf16* __restrict__ pooled) {
    __shared__ __align__(16) unsigned char lds[BB + 2 * BSTG];  // 144 KB
    __shared__ float rs[BM];
    const int t    = threadIdx.x;
    const int lane = t & 63;
    const int wid  = t >> 6;        // 0..7: wave owns 32 rows x 32 cols (cols wid*32)
    const int lrow = lane & 15;
    const int lk4  = lane >> 4;     // 0..3
    const int m0   = blockIdx.x * BM;

    f32x4 acc[2][2];
#pragma unroll
    for (int i = 0; i < 2; ++i)
#pragma unroll
        for (int j = 0; j < 2; ++j) acc[i][j] = {0.f, 0.f, 0.f, 0.f};

    float rsum = 0.f;

    // ---- A staging: thread t -> row t>>4 (0..31), seg t&15 (8 floats = 16 B bf16)
    const int arow = t >> 4;
    const int aseg = t & 15;
    const float* aSrc = A + (size_t)(m0 + arow) * N_NODES + aseg * 8;
    const int awb = arow * 256 + ((aseg ^ (arow & 15)) << 4);   // within A stage

    // ---- B DMA (8 rounds): round r, wave w covers cols (r*8+w)*4 + (lane>>4),
    //      16 segs per col. col&15 is r-invariant -> single base + r*512KB stride.
    //      LDS dest linear: stage + (r*8+wid)*1024 + lane*16 (HW).
    const int bcol0 = wid * 4 + lk4;                 // col for r=0
    const int bseg0 = (lane & 15) ^ (bcol0 & 15);    // logical seg (pre-swizzled src)
    const bf16* bsrc0 = hT + (size_t)bcol0 * N_NODES + bseg0 * 8;
    const int bdst0 = wid * 1024;                    // + r*8192 within stage

    // ---- fragment read byte offsets: 4 kki x (2 A mf + 2 B nf)
    int aOff[4][2], bOff[4][2];
#pragma unroll
    for (int kki = 0; kki < 4; ++kki) {
        int sA = kki * 4 + lk4;
#pragma unroll
        for (int f = 0; f < 2; ++f) {
            int row = f * 16 + lrow;
            aOff[kki][f] = row * 256 + ((sA ^ (row & 15)) << 4);
            int col = wid * 32 + f * 16 + lrow;
            bOff[kki][f] = BB + col * 256 + ((sA ^ (col & 15)) << 4);
        }
    }

    f32x4 ra0, ra1;

#define ALOAD(tile) do {                                                      \
        const float* p_ = aSrc + (size_t)(tile) * BK;                         \
        ra0 = *reinterpret_cast<const f32x4*>(p_);                            \
        ra1 = *reinterpret_cast<const f32x4*>(p_ + 4);                        \
    } while (0)

#define CVTW(st) do {                                                         \
        bf16x8 w_;                                                            \
        _Pragma("unroll")                                                     \
        for (int j_ = 0; j_ < 4; ++j_) {                                      \
            w_[j_]     = (bf16)ra0[j_];                                       \
            w_[4 + j_] = (bf16)ra1[j_];                                       \
            rsum += ra0[j_] + ra1[j_];                                        \
        }                                                                     \
        *reinterpret_cast<bf16x8*>(&lds[(st) * 8192 + awb]) = w_;             \
    } while (0)

#define BDMA(tile, st) do {                                                   \
        _Pragma("unroll")                                                     \
        for (int r_ = 0; r_ < 8; ++r_) {                                      \
            __builtin_amdgcn_global_load_lds(                                 \
                (const __attribute__((address_space(1))) void*)               \
                    (bsrc0 + (size_t)r_ * 32 * N_NODES + (size_t)(tile) * BK),\
                (__attribute__((address_space(3))) void*)                     \
                    &lds[BB + (st) * BSTG + bdst0 + r_ * 8192],               \
                16, 0, 0);                                                    \
        }                                                                     \
    } while (0)

#define COMPUTE(st) do {                                                      \
        _Pragma("unroll")                                                     \
        for (int kki = 0; kki < 4; ++kki) {                                   \
            bf16x8 a0_ = *reinterpret_cast<const bf16x8*>(                    \
                &lds[(st) * 8192 + aOff[kki][0]]);                            \
            bf16x8 a1_ = *reinterpret_cast<const bf16x8*>(                    \
                &lds[(st) * 8192 + aOff[kki][1]]);                            \
            bf16x8 b0_ = *reinterpret_cast<const bf16x8*>(                    \
                &lds[(st) * BSTG + bOff[kki][0]]);                            \
            bf16x8 b1_ = *reinterpret_cast<const bf16x8*>(                    \
                &lds[(st) * BSTG + bOff[kki][1]]);                            \
            acc[0][0] = mfma16(a0_, b0_, acc[0][0]);                          \
            acc[1][0] = mfma16(a1_, b0_, acc[1][0]);                          \
            acc[0][1] = mfma16(a0_, b1_, acc[0][1]);                          \
            acc[1][1] = mfma16(a1_, b1_, acc[1][1]);                          \
        }                                                                     \
    } while (0)

    // ---------------- prologue: [A0:2] [B0:8] -> CVTW waits A0 (vmcnt 8) ->
    // [B0:8, A1:2] -> WAITVM(2) retires B0, leaves A1 -> BAR -> issue B1.
    ALOAD(0);
    BDMA(0, 0);
    CVTW(0);
    ALOAD(1);
    WAITVM(2);
    WAITLGKM;
    BAR;                         // tile 0 ready
    BDMA(1, 1);

    // ---------------- main loop: tiles 0 .. NT-3
    // steady in-flight at WAITVM: [B(tt+1):8, A(tt+2):2] -> retire B, keep A.
    for (int tt = 0; tt < NT - 2; ++tt) {
        CVTW((tt + 1) & 1);      // compiler vmcnt(8) retires A(tt+1) exactly
        COMPUTE(tt & 1);
        ALOAD(tt + 2);
        WAITVM(2);
        WAITLGKM;
        BAR;                     // tile tt+1 ready; stage tt&1 free
        BDMA(tt + 2, tt & 1);
    }
    // ---------------- tail: tiles NT-2, NT-1
    CVTW((NT - 1) & 1);          // compiler vmcnt(8) retires A(NT-1)
    COMPUTE((NT - 2) & 1);
    WAITVM(0);                   // drain B(NT-1)
    WAITLGKM;
    BAR;
    COMPUTE((NT - 1) & 1);

    // ---------------- rowsum: 16 same-row threads (lanes xor 1,2,4,8) reduce
    rsum += __shfl_xor(rsum, 1);
    rsum += __shfl_xor(rsum, 2);
    rsum += __shfl_xor(rsum, 4);
    rsum += __shfl_xor(rsum, 8);
    if ((lane & 15) == 0) rs[wid * 4 + (lane >> 4)] = rsum;   // row = t>>4
    __syncthreads();

    // ---------------- epilogue: pooled = acc / (rs + eps), bf16 direct
#pragma unroll
    for (int mf = 0; mf < 2; ++mf)
#pragma unroll
        for (int nf = 0; nf < 2; ++nf) {
            int col = wid * 32 + nf * 16 + lrow;
#pragma unroll
            for (int j = 0; j < 4; ++j) {
                int row = mf * 16 + lk4 * 4 + j;
                float v = acc[mf][nf][j] / (rs[row] + EPSF);
                pooled[(size_t)(m0 + row) * DOUT + col] = (bf16)v;
            }
        }
#undef ALOAD
#undef CVTW
#undef BDMA
#undef COMPUTE
}

// ---------------- K3: out = relu([X || pooled] @ W_fc + b_fc) + eps, + per-block sumsq partial
__global__ __launch_bounds__(128) void k3_out(const float* __restrict__ X,
                                              const bf16* __restrict__ pooled,
                                              const bf16* __restrict__ WfcT,
                                              const float* __restrict__ bfc,
                                              float* __restrict__ out,
                                              float* __restrict__ partials) {
    const int lane = threadIdx.x & 63;
    const int wid  = threadIdx.x >> 6;
    const int m0   = blockIdx.x * 16;
    const int lrow = lane & 15;
    const int lk8  = (lane >> 4) * 8;

    f32x4 acc[8];
#pragma unroll
    for (int i = 0; i < 8; ++i) acc[i] = {0.f, 0.f, 0.f, 0.f};

#pragma unroll
    for (int ks = 0; ks < 256; ks += 32) {
        const float* xp = X + (size_t)(m0 + lrow) * DIN + ks + lk8;
        f32x4 x0 = *reinterpret_cast<const f32x4*>(xp);
        f32x4 x1 = *reinterpret_cast<const f32x4*>(xp + 4);
        bf16x8 a;
#pragma unroll
        for (int j = 0; j < 4; ++j) { a[j] = (bf16)x0[j]; a[4 + j] = (bf16)x1[j]; }
#pragma unroll
        for (int nb = 0; nb < 8; ++nb) {
            int col = wid * 128 + nb * 16 + lrow;
            bf16x8 b = *reinterpret_cast<const bf16x8*>(WfcT + (size_t)col * KCAT + ks + lk8);
            acc[nb] = mfma16(a, b, acc[nb]);
        }
    }
#pragma unroll
    for (int ks = 256; ks < 512; ks += 32) {
        bf16x8 a = *reinterpret_cast<const bf16x8*>(pooled + (size_t)(m0 + lrow) * DOUT + (ks - 256) + lk8);
#pragma unroll
        for (int nb = 0; nb < 8; ++nb) {
            int col = wid * 128 + nb * 16 + lrow;
            bf16x8 b = *reinterpret_cast<const bf16x8*>(WfcT + (size_t)col * KCAT + ks + lk8);
            acc[nb] = mfma16(a, b, acc[nb]);
        }
    }

    float ss = 0.f;
#pragma unroll
    for (int nb = 0; nb < 8; ++nb) {
        int col = wid * 128 + nb * 16 + lrow;
        float bias = bfc[col];
#pragma unroll
        for (int j = 0; j < 4; ++j) {
            int row = m0 + (lane >> 4) * 4 + j;
            float v = acc[nb][j] + bias;
            v = (v > 0.f ? v : 0.f) + EPSF;
            out[(size_t)row * DOUT + col] = v;
            ss += v * v;
        }
    }
#pragma unroll
    for (int off = 32; off; off >>= 1) ss += __shfl_xor(ss, off);
    __shared__ float sw[2];
    if (lane == 0) sw[wid] = ss;
    __syncthreads();
    if (threadIdx.x == 0) partials[blockIdx.x] = sw[0] + sw[1];
}

// ---------------- K4: deterministic reduce of 512 partials; scale out by 1/(norm+eps)
__global__ __launch_bounds__(256) void k4_norm(float* __restrict__ out,
                                               const float* __restrict__ partials) {
    __shared__ float sw[4];
    float s = partials[threadIdx.x] + partials[threadIdx.x + 256];
#pragma unroll
    for (int off = 32; off; off >>= 1) s += __shfl_xor(s, off);
    if ((threadIdx.x & 63) == 0) sw[threadIdx.x >> 6] = s;
    __syncthreads();
    float total = sw[0] + sw[1] + sw[2] + sw[3];
    float scale = 1.f / (sqrtf(total) + EPSF);
    f32x4* o4 = reinterpret_cast<f32x4*>(out);
    const int nvec = N_NODES * DOUT / 4;
    for (int i = blockIdx.x * blockDim.x + threadIdx.x; i < nvec; i += gridDim.x * blockDim.x) {
        f32x4 v = o4[i];
#pragma unroll
        for (int j = 0; j < 4; ++j) v[j] *= scale;
        o4[i] = v;
    }
}

extern "C" void kernel_launch(void* const* d_in, const int* in_sizes, int n_in,
                              void* d_out, int out_size, void* d_ws, size_t ws_size,
                              hipStream_t stream) {
    const float* A   = (const float*)d_in[0];
    const float* X   = (const float*)d_in[1];
    const float* Ww  = (const float*)d_in[2];
    const float* bw  = (const float*)d_in[3];
    const float* Wfc = (const float*)d_in[4];
    const float* bfc = (const float*)d_in[5];
    float* out = (float*)d_out;

    char* ws = (char*)d_ws;
    bf16*  hT        = (bf16*)(ws);                                  // 4 MiB
    bf16*  pooled    = (bf16*)(ws + (4u << 20));                     // 4 MiB
    bf16*  WwT       = (bf16*)(ws + (8u << 20));                     // 128 KiB
    bf16*  WfcT      = (bf16*)(ws + (8u << 20) + (128u << 10));      // 256 KiB
    float* partials  = (float*)(ws + (8u << 20) + (384u << 10));     // 2 KiB

    k0_prep<<<512, 256, 0, stream>>>(Ww, Wfc, WwT, WfcT);
    k1_h<<<512, 128, 0, stream>>>(X, WwT, bw, hT);
    k2_pool<<<256, 512, 0, stream>>>(A, hT, pooled);
    k3_out<<<512, 128, 0, stream>>>(X, pooled, WfcT, bfc, out, partials);
    k4_norm<<<256, 256, 0, stream>>>(out, partials);
}

// Round 12
// 151.977 us; speedup vs baseline: 1.2260x; 1.0000x over previous
//
#include <hip/hip_runtime.h>
#include <hip/hip_bf16.h>
#include <math.h>

typedef __bf16 bf16;
typedef bf16 bf16x8 __attribute__((ext_vector_type(8)));
typedef bf16 bf16x4 __attribute__((ext_vector_type(4)));
typedef float f32x4 __attribute__((ext_vector_type(4)));

#define N_NODES 8192
#define DIN 256
#define DOUT 256
#define KCAT 512
#define EPSF 1e-8f
#define BM 32
#define BK 128
#define NT (N_NODES / BK)   // 64 tiles, full K per block (KSPLIT=1)
#define BB 16384            // B region base (A: 2 stages x 8 KB)
#define BSTG 65536          // B stage size (256 cols x 256 B)

__device__ __forceinline__ f32x4 mfma16(bf16x8 a, bf16x8 b, f32x4 c) {
    return __builtin_amdgcn_mfma_f32_16x16x32_bf16(a, b, c, 0, 0, 0);
}

#define WAITVM(N) asm volatile("s_waitcnt vmcnt(" #N ")" ::: "memory")
#define WAITLGKM  asm volatile("s_waitcnt lgkmcnt(0)" ::: "memory")
#define BAR       __builtin_amdgcn_s_barrier()

// ---------------- K0: W_w [256x256] -> WwT[n][k] bf16 ; W_fc [512x256] -> WfcT[n][k] bf16
__global__ __launch_bounds__(256) void k0_prep(const float* __restrict__ Ww,
                                               const float* __restrict__ Wfc,
                                               bf16* __restrict__ WwT,
                                               bf16* __restrict__ WfcT) {
    int tid = blockIdx.x * 256 + threadIdx.x;
    if (tid < 256 * 256) {
        int n = tid >> 8, k = tid & 255;
        WwT[n * 256 + k] = (bf16)Ww[k * 256 + n];
    }
    if (tid < 256 * 512) {
        int n = tid >> 9, k = tid & 511;
        WfcT[n * 512 + k] = (bf16)Wfc[k * 256 + n];
    }
}

// ---------------- K1: hT[col][m] = bf16(relu(X @ W_w + b_w))
__global__ __launch_bounds__(128) void k1_h(const float* __restrict__ X,
                                            const bf16* __restrict__ WwT,
                                            const float* __restrict__ bw,
                                            bf16* __restrict__ hT) {
    const int lane = threadIdx.x & 63;
    const int wid  = threadIdx.x >> 6;   // 0..1
    const int m0   = blockIdx.x * 16;
    const int lrow = lane & 15;
    const int lk8  = (lane >> 4) * 8;

    f32x4 acc[8];
#pragma unroll
    for (int i = 0; i < 8; ++i) acc[i] = {0.f, 0.f, 0.f, 0.f};

#pragma unroll
    for (int ks = 0; ks < DIN; ks += 32) {
        const float* xp = X + (size_t)(m0 + lrow) * DIN + ks + lk8;
        f32x4 x0 = *reinterpret_cast<const f32x4*>(xp);
        f32x4 x1 = *reinterpret_cast<const f32x4*>(xp + 4);
        bf16x8 a;
#pragma unroll
        for (int j = 0; j < 4; ++j) { a[j] = (bf16)x0[j]; a[4 + j] = (bf16)x1[j]; }
#pragma unroll
        for (int nb = 0; nb < 8; ++nb) {
            int col = wid * 128 + nb * 16 + lrow;
            bf16x8 b = *reinterpret_cast<const bf16x8*>(WwT + (size_t)col * DIN + ks + lk8);
            acc[nb] = mfma16(a, b, acc[nb]);
        }
    }
    const int mrow = m0 + (lane >> 4) * 4;
#pragma unroll
    for (int nb = 0; nb < 8; ++nb) {
        int col = wid * 128 + nb * 16 + lrow;
        float bias = bw[col];
        bf16x4 hv;
#pragma unroll
        for (int j = 0; j < 4; ++j) {
            float v = acc[nb][j] + bias;
            hv[j] = (bf16)(v > 0.f ? v : 0.f);
        }
        *reinterpret_cast<bf16x4*>(hT + (size_t)col * N_NODES + mrow) = hv;
    }
}

// ---------------- K2: pooled = (A @ h) / (rowsum(A)+eps), bf16 out — KSPLIT=1
// DRAM-STREAM PROBE: one block owns 32 FULL rows of A (BM=32, BK=128, NT=64,
// grid=256). Each A-row is ONE strictly sequential stream (8192 streams
// ~8/channel -> DRAM open-page friendly) instead of 4-8 interleaved k-phase
// pointers per row (~256 streams/channel) as in all KSPLIT>=4 configs — the
// last untested invariant behind the ~3.6 TB/s pattern ceiling.
// B = ALL of hT, streamed per-tile from L2/L3 via global_load_lds (64 KB/tile,
// source-pre-swizzled, linear dest). A: coalesced f32x4 -> cvt -> swizzled
// ds_write (8 KB/tile). Both dbuf; R3's proven 1-barrier counted-vmcnt ladder
// re-traced for (2 A-loads + 8 B-DMAs)/tile: steady WAITVM(2) retires B(t+1),
// leaves A(t+2). Swizzle: 256 B row pitch, phys_seg = seg ^ (row&15) (2-way
// bank aliasing only = free). Rowsum fused into staging VALU + 4 shfl —
// k2 writes pooled bf16 DIRECTLY (no part/rsG buffers at all).
__global__ __launch_bounds__(512) void k2_pool(const float* __restrict__ A,
                                               const bf16* __restrict__ hT,
                                               bf16* __restrict__ pooled) {
    __shared__ __align__(16) unsigned char lds[BB + 2 * BSTG];  // 144 KB
    __shared__ float rs[BM];
    const int t    = threadIdx.x;
    const int lane = t & 63;
    const int wid  = t >> 6;        // 0..7: wave owns 32 rows x 32 cols (cols wid*32)
    const int lrow = lane & 15;
    const int lk4  = lane >> 4;     // 0..3
    const int m0   = blockIdx.x * BM;

    f32x4 acc[2][2];
#pragma unroll
    for (int i = 0; i < 2; ++i)
#pragma unroll
        for (int j = 0; j < 2; ++j) acc[i][j] = {0.f, 0.f, 0.f, 0.f};

    float rsum = 0.f;

    // ---- A staging: thread t -> row t>>4 (0..31), seg t&15 (8 floats = 16 B bf16)
    const int arow = t >> 4;
    const int aseg = t & 15;
    const float* aSrc = A + (size_t)(m0 + arow) * N_NODES + aseg * 8;
    const int awb = arow * 256 + ((aseg ^ (arow & 15)) << 4);   // within A stage

    // ---- B DMA (8 rounds): round r, wave w covers cols (r*8+w)*4 + (lane>>4),
    //      16 segs per col. col&15 is r-invariant -> single base + r*512KB stride.
    //      LDS dest linear: stage + (r*8+wid)*1024 + lane*16 (HW).
    const int bcol0 = wid * 4 + lk4;                 // col for r=0
    const int bseg0 = (lane & 15) ^ (bcol0 & 15);    // logical seg (pre-swizzled src)
    const bf16* bsrc0 = hT + (size_t)bcol0 * N_NODES + bseg0 * 8;
    const int bdst0 = wid * 1024;                    // + r*8192 within stage

    // ---- fragment read byte offsets: 4 kki x (2 A mf + 2 B nf)
    int aOff[4][2], bOff[4][2];
#pragma unroll
    for (int kki = 0; kki < 4; ++kki) {
        int sA = kki * 4 + lk4;
#pragma unroll
        for (int f = 0; f < 2; ++f) {
            int row = f * 16 + lrow;
            aOff[kki][f] = row * 256 + ((sA ^ (row & 15)) << 4);
            int col = wid * 32 + f * 16 + lrow;
            bOff[kki][f] = BB + col * 256 + ((sA ^ (col & 15)) << 4);
        }
    }

    f32x4 ra0, ra1;

#define ALOAD(tile) do {                                                      \
        const float* p_ = aSrc + (size_t)(tile) * BK;                         \
        ra0 = *reinterpret_cast<const f32x4*>(p_);                            \
        ra1 = *reinterpret_cast<const f32x4*>(p_ + 4);                        \
    } while (0)

#define CVTW(st) do {                                                         \
        bf16x8 w_;                                                            \
        _Pragma("unroll")                                                     \
        for (int j_ = 0; j_ < 4; ++j_) {                                      \
            w_[j_]     = (bf16)ra0[j_];                                       \
            w_[4 + j_] = (bf16)ra1[j_];                                       \
            rsum += ra0[j_] + ra1[j_];                                        \
        }                                                                     \
        *reinterpret_cast<bf16x8*>(&lds[(st) * 8192 + awb]) = w_;             \
    } while (0)

#define BDMA(tile, st) do {                                                   \
        _Pragma("unroll")                                                     \
        for (int r_ = 0; r_ < 8; ++r_) {                                      \
            __builtin_amdgcn_global_load_lds(                                 \
                (const __attribute__((address_space(1))) void*)               \
                    (bsrc0 + (size_t)r_ * 32 * N_NODES + (size_t)(tile) * BK),\
                (__attribute__((address_space(3))) void*)                     \
                    &lds[BB + (st) * BSTG + bdst0 + r_ * 8192],               \
                16, 0, 0);                                                    \
        }                                                                     \
    } while (0)

#define COMPUTE(st) do {                                                      \
        _Pragma("unroll")                                                     \
        for (int kki = 0; kki < 4; ++kki) {                                   \
            bf16x8 a0_ = *reinterpret_cast<const bf16x8*>(                    \
                &lds[(st) * 8192 + aOff[kki][0]]);                            \
            bf16x8 a1_ = *reinterpret_cast<const bf16x8*>(                    \
                &lds[(st) * 8192 + aOff[kki][1]]);                            \
            bf16x8 b0_ = *reinterpret_cast<const bf16x8*>(                    \
                &lds[(st) * BSTG + bOff[kki][0]]);                            \
            bf16x8 b1_ = *reinterpret_cast<const bf16x8*>(                    \
                &lds[(st) * BSTG + bOff[kki][1]]);                            \
            acc[0][0] = mfma16(a0_, b0_, acc[0][0]);                          \
            acc[1][0] = mfma16(a1_, b0_, acc[1][0]);                          \
            acc[0][1] = mfma16(a0_, b1_, acc[0][1]);                          \
            acc[1][1] = mfma16(a1_, b1_, acc[1][1]);                          \
        }                                                                     \
    } while (0)

    // ---------------- prologue: [A0:2] [B0:8] -> CVTW waits A0 (vmcnt 8) ->
    // [B0:8, A1:2] -> WAITVM(2) retires B0, leaves A1 -> BAR -> issue B1.
    ALOAD(0);
    BDMA(0, 0);
    CVTW(0);
    ALOAD(1);
    WAITVM(2);
    WAITLGKM;
    BAR;                         // tile 0 ready
    BDMA(1, 1);

    // ---------------- main loop: tiles 0 .. NT-3
    // steady in-flight at WAITVM: [B(tt+1):8, A(tt+2):2] -> retire B, keep A.
    for (int tt = 0; tt < NT - 2; ++tt) {
        CVTW((tt + 1) & 1);      // compiler vmcnt(8) retires A(tt+1) exactly
        COMPUTE(tt & 1);
        ALOAD(tt + 2);
        WAITVM(2);
        WAITLGKM;
        BAR;                     // tile tt+1 ready; stage tt&1 free
        BDMA(tt + 2, tt & 1);
    }
    // ---------------- tail: tiles NT-2, NT-1
    CVTW((NT - 1) & 1);          // compiler vmcnt(8) retires A(NT-1)
    COMPUTE((NT - 2) & 1);
    WAITVM(0);                   // drain B(NT-1)
    WAITLGKM;
    BAR;
    COMPUTE((NT - 1) & 1);

    // ---------------- rowsum: 16 same-row threads (lanes xor 1,2,4,8) reduce
    rsum += __shfl_xor(rsum, 1);
    rsum += __shfl_xor(rsum, 2);
    rsum += __shfl_xor(rsum, 4);
    rsum += __shfl_xor(rsum, 8);
    if ((lane & 15) == 0) rs[wid * 4 + (lane >> 4)] = rsum;   // row = t>>4
    __syncthreads();

    // ---------------- epilogue: pooled = acc / (rs + eps), bf16 direct
#pragma unroll
    for (int mf = 0; mf < 2; ++mf)
#pragma unroll
        for (int nf = 0; nf < 2; ++nf) {
            int col = wid * 32 + nf * 16 + lrow;
#pragma unroll
            for (int j = 0; j < 4; ++j) {
                int row = mf * 16 + lk4 * 4 + j;
                float v = acc[mf][nf][j] / (rs[row] + EPSF);
                pooled[(size_t)(m0 + row) * DOUT + col] = (bf16)v;
            }
        }
#undef ALOAD
#undef CVTW
#undef BDMA
#undef COMPUTE
}

// ---------------- K3: out = relu([X || pooled] @ W_fc + b_fc) + eps, + per-block sumsq partial
__global__ __launch_bounds__(128) void k3_out(const float* __restrict__ X,
                                              const bf16* __restrict__ pooled,
                                              const bf16* __restrict__ WfcT,
                                              const float* __restrict__ bfc,
                                              float* __restrict__ out,
                                              float* __restrict__ partials) {
    const int lane = threadIdx.x & 63;
    const int wid  = threadIdx.x >> 6;
    const int m0   = blockIdx.x * 16;
    const int lrow = lane & 15;
    const int lk8  = (lane >> 4) * 8;

    f32x4 acc[8];
#pragma unroll
    for (int i = 0; i < 8; ++i) acc[i] = {0.f, 0.f, 0.f, 0.f};

#pragma unroll
    for (int ks = 0; ks < 256; ks += 32) {
        const float* xp = X + (size_t)(m0 + lrow) * DIN + ks + lk8;
        f32x4 x0 = *reinterpret_cast<const f32x4*>(xp);
        f32x4 x1 = *reinterpret_cast<const f32x4*>(xp + 4);
        bf16x8 a;
#pragma unroll
        for (int j = 0; j < 4; ++j) { a[j] = (bf16)x0[j]; a[4 + j] = (bf16)x1[j]; }
#pragma unroll
        for (int nb = 0; nb < 8; ++nb) {
            int col = wid * 128 + nb * 16 + lrow;
            bf16x8 b = *reinterpret_cast<const bf16x8*>(WfcT + (size_t)col * KCAT + ks + lk8);
            acc[nb] = mfma16(a, b, acc[nb]);
        }
    }
#pragma unroll
    for (int ks = 256; ks < 512; ks += 32) {
        bf16x8 a = *reinterpret_cast<const bf16x8*>(pooled + (size_t)(m0 + lrow) * DOUT + (ks - 256) + lk8);
#pragma unroll
        for (int nb = 0; nb < 8; ++nb) {
            int col = wid * 128 + nb * 16 + lrow;
            bf16x8 b = *reinterpret_cast<const bf16x8*>(WfcT + (size_t)col * KCAT + ks + lk8);
            acc[nb] = mfma16(a, b, acc[nb]);
        }
    }

    float ss = 0.f;
#pragma unroll
    for (int nb = 0; nb < 8; ++nb) {
        int col = wid * 128 + nb * 16 + lrow;
        float bias = bfc[col];
#pragma unroll
        for (int j = 0; j < 4; ++j) {
            int row = m0 + (lane >> 4) * 4 + j;
            float v = acc[nb][j] + bias;
            v = (v > 0.f ? v : 0.f) + EPSF;
            out[(size_t)row * DOUT + col] = v;
            ss += v * v;
        }
    }
#pragma unroll
    for (int off = 32; off; off >>= 1) ss += __shfl_xor(ss, off);
    __shared__ float sw[2];
    if (lane == 0) sw[wid] = ss;
    __syncthreads();
    if (threadIdx.x == 0) partials[blockIdx.x] = sw[0] + sw[1];
}

// ---------------- K4: deterministic reduce of 512 partials; scale out by 1/(norm+eps)
__global__ __launch_bounds__(256) void k4_norm(float* __restrict__ out,
                                               const float* __restrict__ partials) {
    __shared__ float sw[4];
    float s = partials[threadIdx.x] + partials[threadIdx.x + 256];
#pragma unroll
    for (int off = 32; off; off >>= 1) s += __shfl_xor(s, off);
    if ((threadIdx.x & 63) == 0) sw[threadIdx.x >> 6] = s;
    __syncthreads();
    float total = sw[0] + sw[1] + sw[2] + sw[3];
    float scale = 1.f / (sqrtf(total) + EPSF);
    f32x4* o4 = reinterpret_cast<f32x4*>(out);
    const int nvec = N_NODES * DOUT / 4;
    for (int i = blockIdx.x * blockDim.x + threadIdx.x; i < nvec; i += gridDim.x * blockDim.x) {
        f32x4 v = o4[i];
#pragma unroll
        for (int j = 0; j < 4; ++j) v[j] *= scale;
        o4[i] = v;
    }
}

extern "C" void kernel_launch(void* const* d_in, const int* in_sizes, int n_in,
                              void* d_out, int out_size, void* d_ws, size_t ws_size,
                              hipStream_t stream) {
    const float* A   = (const float*)d_in[0];
    const float* X   = (const float*)d_in[1];
    const float* Ww  = (const float*)d_in[2];
    const float* bw  = (const float*)d_in[3];
    const float* Wfc = (const float*)d_in[4];
    const float* bfc = (const float*)d_in[5];
    float* out = (float*)d_out;

    char* ws = (char*)d_ws;
    bf16*  hT        = (bf16*)(ws);                                  // 4 MiB
    bf16*  pooled    = (bf16*)(ws + (4u << 20));                     // 4 MiB
    bf16*  WwT       = (bf16*)(ws + (8u << 20));                     // 128 KiB
    bf16*  WfcT      = (bf16*)(ws + (8u << 20) + (128u << 10));      // 256 KiB
    float* partials  = (float*)(ws + (8u << 20) + (384u << 10));     // 2 KiB

    k0_prep<<<512, 256, 0, stream>>>(Ww, Wfc, WwT, WfcT);
    k1_h<<<512, 128, 0, stream>>>(X, WwT, bw, hT);
    k2_pool<<<256, 512, 0, stream>>>(A, hT, pooled);
    k3_out<<<512, 128, 0, stream>>>(X, pooled, WfcT, bfc, out, partials);
    k4_norm<<<256, 256, 0, stream>>>(out, partials);
}

// Round 13
// 151.669 us; speedup vs baseline: 1.2284x; 1.0020x over previous
//
#include <hip/hip_runtime.h>
#include <hip/hip_bf16.h>
#include <math.h>

typedef __bf16 bf16;
typedef bf16 bf16x8 __attribute__((ext_vector_type(8)));
typedef bf16 bf16x4 __attribute__((ext_vector_type(4)));
typedef float f32x4 __attribute__((ext_vector_type(4)));

#define N_NODES 8192
#define DIN 256
#define DOUT 256
#define KCAT 512
#define EPSF 1e-8f
#define BM 32
#define BK 128
#define NT (N_NODES / BK)   // 64 tiles, full K per block (KSPLIT=1)
#define BB 16384            // B region base (A: 2 stages x 8 KB)
#define BSTG 65536          // B stage size (256 cols x 256 B)

__device__ __forceinline__ f32x4 mfma16(bf16x8 a, bf16x8 b, f32x4 c) {
    return __builtin_amdgcn_mfma_f32_16x16x32_bf16(a, b, c, 0, 0, 0);
}

#define WAITVM(N) asm volatile("s_waitcnt vmcnt(" #N ")" ::: "memory")
#define WAITLGKM  asm volatile("s_waitcnt lgkmcnt(0)" ::: "memory")
#define BAR       __builtin_amdgcn_s_barrier()

// ---------------- K0: W_w [256x256] -> WwT[n][k] bf16 ; W_fc [512x256] -> WfcT[n][k] bf16
__global__ __launch_bounds__(256) void k0_prep(const float* __restrict__ Ww,
                                               const float* __restrict__ Wfc,
                                               bf16* __restrict__ WwT,
                                               bf16* __restrict__ WfcT) {
    int tid = blockIdx.x * 256 + threadIdx.x;
    if (tid < 256 * 256) {
        int n = tid >> 8, k = tid & 255;
        WwT[n * 256 + k] = (bf16)Ww[k * 256 + n];
    }
    if (tid < 256 * 512) {
        int n = tid >> 9, k = tid & 511;
        WfcT[n * 512 + k] = (bf16)Wfc[k * 256 + n];
    }
}

// ---------------- K1: hT[col][m] = bf16(relu(X @ W_w + b_w))
__global__ __launch_bounds__(128) void k1_h(const float* __restrict__ X,
                                            const bf16* __restrict__ WwT,
                                            const float* __restrict__ bw,
                                            bf16* __restrict__ hT) {
    const int lane = threadIdx.x & 63;
    const int wid  = threadIdx.x >> 6;   // 0..1
    const int m0   = blockIdx.x * 16;
    const int lrow = lane & 15;
    const int lk8  = (lane >> 4) * 8;

    f32x4 acc[8];
#pragma unroll
    for (int i = 0; i < 8; ++i) acc[i] = {0.f, 0.f, 0.f, 0.f};

#pragma unroll
    for (int ks = 0; ks < DIN; ks += 32) {
        const float* xp = X + (size_t)(m0 + lrow) * DIN + ks + lk8;
        f32x4 x0 = *reinterpret_cast<const f32x4*>(xp);
        f32x4 x1 = *reinterpret_cast<const f32x4*>(xp + 4);
        bf16x8 a;
#pragma unroll
        for (int j = 0; j < 4; ++j) { a[j] = (bf16)x0[j]; a[4 + j] = (bf16)x1[j]; }
#pragma unroll
        for (int nb = 0; nb < 8; ++nb) {
            int col = wid * 128 + nb * 16 + lrow;
            bf16x8 b = *reinterpret_cast<const bf16x8*>(WwT + (size_t)col * DIN + ks + lk8);
            acc[nb] = mfma16(a, b, acc[nb]);
        }
    }
    const int mrow = m0 + (lane >> 4) * 4;
#pragma unroll
    for (int nb = 0; nb < 8; ++nb) {
        int col = wid * 128 + nb * 16 + lrow;
        float bias = bw[col];
        bf16x4 hv;
#pragma unroll
        for (int j = 0; j < 4; ++j) {
            float v = acc[nb][j] + bias;
            hv[j] = (bf16)(v > 0.f ? v : 0.f);
        }
        *reinterpret_cast<bf16x4*>(hT + (size_t)col * N_NODES + mrow) = hv;
    }
}

// ---------------- K2: pooled = (A @ h) / (rowsum(A)+eps), bf16 out — KSPLIT=1
// DRAM-STREAM PROBE: one block owns 32 FULL rows of A (BM=32, BK=128, NT=64,
// grid=256). Each A-row is ONE strictly sequential stream (8192 streams
// ~8/channel -> DRAM open-page friendly) instead of 4-8 interleaved k-phase
// pointers per row (~256 streams/channel) as in all KSPLIT>=4 configs — the
// last untested invariant behind the ~3.6 TB/s pattern ceiling.
// B = ALL of hT, streamed per-tile from L2/L3 via global_load_lds (64 KB/tile,
// source-pre-swizzled, linear dest). A: coalesced f32x4 -> cvt -> swizzled
// ds_write (8 KB/tile). Both dbuf; R3's proven 1-barrier counted-vmcnt ladder
// re-traced for (2 A-loads + 8 B-DMAs)/tile: steady WAITVM(2) retires B(t+1),
// leaves A(t+2). Swizzle: 256 B row pitch, phys_seg = seg ^ (row&15) (2-way
// bank aliasing only = free). Rowsum fused into staging VALU + 4 shfl —
// k2 writes pooled bf16 DIRECTLY (no part/rsG buffers at all).
__global__ __launch_bounds__(512) void k2_pool(const float* __restrict__ A,
                                               const bf16* __restrict__ hT,
                                               bf16* __restrict__ pooled) {
    __shared__ __align__(16) unsigned char lds[BB + 2 * BSTG];  // 144 KB
    __shared__ float rs[BM];
    const int t    = threadIdx.x;
    const int lane = t & 63;
    const int wid  = t >> 6;        // 0..7: wave owns 32 rows x 32 cols (cols wid*32)
    const int lrow = lane & 15;
    const int lk4  = lane >> 4;     // 0..3
    const int m0   = blockIdx.x * BM;

    f32x4 acc[2][2];
#pragma unroll
    for (int i = 0; i < 2; ++i)
#pragma unroll
        for (int j = 0; j < 2; ++j) acc[i][j] = {0.f, 0.f, 0.f, 0.f};

    float rsum = 0.f;

    // ---- A staging: thread t -> row t>>4 (0..31), seg t&15 (8 floats = 16 B bf16)
    const int arow = t >> 4;
    const int aseg = t & 15;
    const float* aSrc = A + (size_t)(m0 + arow) * N_NODES + aseg * 8;
    const int awb = arow * 256 + ((aseg ^ (arow & 15)) << 4);   // within A stage

    // ---- B DMA (8 rounds): round r, wave w covers cols (r*8+w)*4 + (lane>>4),
    //      16 segs per col. col&15 is r-invariant -> single base + r*512KB stride.
    //      LDS dest linear: stage + (r*8+wid)*1024 + lane*16 (HW).
    const int bcol0 = wid * 4 + lk4;                 // col for r=0
    const int bseg0 = (lane & 15) ^ (bcol0 & 15);    // logical seg (pre-swizzled src)
    const bf16* bsrc0 = hT + (size_t)bcol0 * N_NODES + bseg0 * 8;
    const int bdst0 = wid * 1024;                    // + r*8192 within stage

    // ---- fragment read byte offsets: 4 kki x (2 A mf + 2 B nf)
    int aOff[4][2], bOff[4][2];
#pragma unroll
    for (int kki = 0; kki < 4; ++kki) {
        int sA = kki * 4 + lk4;
#pragma unroll
        for (int f = 0; f < 2; ++f) {
            int row = f * 16 + lrow;
            aOff[kki][f] = row * 256 + ((sA ^ (row & 15)) << 4);
            int col = wid * 32 + f * 16 + lrow;
            bOff[kki][f] = BB + col * 256 + ((sA ^ (col & 15)) << 4);
        }
    }

    f32x4 ra0, ra1;

#define ALOAD(tile) do {                                                      \
        const float* p_ = aSrc + (size_t)(tile) * BK;                         \
        ra0 = *reinterpret_cast<const f32x4*>(p_);                            \
        ra1 = *reinterpret_cast<const f32x4*>(p_ + 4);                        \
    } while (0)

#define CVTW(st) do {                                                         \
        bf16x8 w_;                                                            \
        _Pragma("unroll")                                                     \
        for (int j_ = 0; j_ < 4; ++j_) {                                      \
            w_[j_]     = (bf16)ra0[j_];                                       \
            w_[4 + j_] = (bf16)ra1[j_];                                       \
            rsum += ra0[j_] + ra1[j_];                                        \
        }                                                                     \
        *reinterpret_cast<bf16x8*>(&lds[(st) * 8192 + awb]) = w_;             \
    } while (0)

#define BDMA(tile, st) do {                                                   \
        _Pragma("unroll")                                                     \
        for (int r_ = 0; r_ < 8; ++r_) {                                      \
            __builtin_amdgcn_global_load_lds(                                 \
                (const __attribute__((address_space(1))) void*)               \
                    (bsrc0 + (size_t)r_ * 32 * N_NODES + (size_t)(tile) * BK),\
                (__attribute__((address_space(3))) void*)                     \
                    &lds[BB + (st) * BSTG + bdst0 + r_ * 8192],               \
                16, 0, 0);                                                    \
        }                                                                     \
    } while (0)

#define COMPUTE(st) do {                                                      \
        _Pragma("unroll")                                                     \
        for (int kki = 0; kki < 4; ++kki) {                                   \
            bf16x8 a0_ = *reinterpret_cast<const bf16x8*>(                    \
                &lds[(st) * 8192 + aOff[kki][0]]);                            \
            bf16x8 a1_ = *reinterpret_cast<const bf16x8*>(                    \
                &lds[(st) * 8192 + aOff[kki][1]]);                            \
            bf16x8 b0_ = *reinterpret_cast<const bf16x8*>(                    \
                &lds[(st) * BSTG + bOff[kki][0]]);                            \
            bf16x8 b1_ = *reinterpret_cast<const bf16x8*>(                    \
                &lds[(st) * BSTG + bOff[kki][1]]);                            \
            acc[0][0] = mfma16(a0_, b0_, acc[0][0]);                          \
            acc[1][0] = mfma16(a1_, b0_, acc[1][0]);                          \
            acc[0][1] = mfma16(a0_, b1_, acc[0][1]);                          \
            acc[1][1] = mfma16(a1_, b1_, acc[1][1]);                          \
        }                                                                     \
    } while (0)

    // ---------------- prologue: [A0:2] [B0:8] -> CVTW waits A0 (vmcnt 8) ->
    // [B0:8, A1:2] -> WAITVM(2) retires B0, leaves A1 -> BAR -> issue B1.
    ALOAD(0);
    BDMA(0, 0);
    CVTW(0);
    ALOAD(1);
    WAITVM(2);
    WAITLGKM;
    BAR;                         // tile 0 ready
    BDMA(1, 1);

    // ---------------- main loop: tiles 0 .. NT-3
    // steady in-flight at WAITVM: [B(tt+1):8, A(tt+2):2] -> retire B, keep A.
    for (int tt = 0; tt < NT - 2; ++tt) {
        CVTW((tt + 1) & 1);      // compiler vmcnt(8) retires A(tt+1) exactly
        COMPUTE(tt & 1);
        ALOAD(tt + 2);
        WAITVM(2);
        WAITLGKM;
        BAR;                     // tile tt+1 ready; stage tt&1 free
        BDMA(tt + 2, tt & 1);
    }
    // ---------------- tail: tiles NT-2, NT-1
    CVTW((NT - 1) & 1);          // compiler vmcnt(8) retires A(NT-1)
    COMPUTE((NT - 2) & 1);
    WAITVM(0);                   // drain B(NT-1)
    WAITLGKM;
    BAR;
    COMPUTE((NT - 1) & 1);

    // ---------------- rowsum: 16 same-row threads (lanes xor 1,2,4,8) reduce
    rsum += __shfl_xor(rsum, 1);
    rsum += __shfl_xor(rsum, 2);
    rsum += __shfl_xor(rsum, 4);
    rsum += __shfl_xor(rsum, 8);
    if ((lane & 15) == 0) rs[wid * 4 + (lane >> 4)] = rsum;   // row = t>>4
    __syncthreads();

    // ---------------- epilogue: pooled = acc / (rs + eps), bf16 direct
#pragma unroll
    for (int mf = 0; mf < 2; ++mf)
#pragma unroll
        for (int nf = 0; nf < 2; ++nf) {
            int col = wid * 32 + nf * 16 + lrow;
#pragma unroll
            for (int j = 0; j < 4; ++j) {
                int row = mf * 16 + lk4 * 4 + j;
                float v = acc[mf][nf][j] / (rs[row] + EPSF);
                pooled[(size_t)(m0 + row) * DOUT + col] = (bf16)v;
            }
        }
#undef ALOAD
#undef CVTW
#undef BDMA
#undef COMPUTE
}

// ---------------- K3: out = relu([X || pooled] @ W_fc + b_fc) + eps, + per-block sumsq partial
__global__ __launch_bounds__(128) void k3_out(const float* __restrict__ X,
                                              const bf16* __restrict__ pooled,
                                              const bf16* __restrict__ WfcT,
                                              const float* __restrict__ bfc,
                                              float* __restrict__ out,
                                              float* __restrict__ partials) {
    const int lane = threadIdx.x & 63;
    const int wid  = threadIdx.x >> 6;
    const int m0   = blockIdx.x * 16;
    const int lrow = lane & 15;
    const int lk8  = (lane >> 4) * 8;

    f32x4 acc[8];
#pragma unroll
    for (int i = 0; i < 8; ++i) acc[i] = {0.f, 0.f, 0.f, 0.f};

#pragma unroll
    for (int ks = 0; ks < 256; ks += 32) {
        const float* xp = X + (size_t)(m0 + lrow) * DIN + ks + lk8;
        f32x4 x0 = *reinterpret_cast<const f32x4*>(xp);
        f32x4 x1 = *reinterpret_cast<const f32x4*>(xp + 4);
        bf16x8 a;
#pragma unroll
        for (int j = 0; j < 4; ++j) { a[j] = (bf16)x0[j]; a[4 + j] = (bf16)x1[j]; }
#pragma unroll
        for (int nb = 0; nb < 8; ++nb) {
            int col = wid * 128 + nb * 16 + lrow;
            bf16x8 b = *reinterpret_cast<const bf16x8*>(WfcT + (size_t)col * KCAT + ks + lk8);
            acc[nb] = mfma16(a, b, acc[nb]);
        }
    }
#pragma unroll
    for (int ks = 256; ks < 512; ks += 32) {
        bf16x8 a = *reinterpret_cast<const bf16x8*>(pooled + (size_t)(m0 + lrow) * DOUT + (ks - 256) + lk8);
#pragma unroll
        for (int nb = 0; nb < 8; ++nb) {
            int col = wid * 128 + nb * 16 + lrow;
            bf16x8 b = *reinterpret_cast<const bf16x8*>(WfcT + (size_t)col * KCAT + ks + lk8);
            acc[nb] = mfma16(a, b, acc[nb]);
        }
    }

    float ss = 0.f;
#pragma unroll
    for (int nb = 0; nb < 8; ++nb) {
        int col = wid * 128 + nb * 16 + lrow;
        float bias = bfc[col];
#pragma unroll
        for (int j = 0; j < 4; ++j) {
            int row = m0 + (lane >> 4) * 4 + j;
            float v = acc[nb][j] + bias;
            v = (v > 0.f ? v : 0.f) + EPSF;
            out[(size_t)row * DOUT + col] = v;
            ss += v * v;
        }
    }
#pragma unroll
    for (int off = 32; off; off >>= 1) ss += __shfl_xor(ss, off);
    __shared__ float sw[2];
    if (lane == 0) sw[wid] = ss;
    __syncthreads();
    if (threadIdx.x == 0) partials[blockIdx.x] = sw[0] + sw[1];
}

// ---------------- K4: deterministic reduce of 512 partials; scale out by 1/(norm+eps)
__global__ __launch_bounds__(256) void k4_norm(float* __restrict__ out,
                                               const float* __restrict__ partials) {
    __shared__ float sw[4];
    float s = partials[threadIdx.x] + partials[threadIdx.x + 256];
#pragma unroll
    for (int off = 32; off; off >>= 1) s += __shfl_xor(s, off);
    if ((threadIdx.x & 63) == 0) sw[threadIdx.x >> 6] = s;
    __syncthreads();
    float total = sw[0] + sw[1] + sw[2] + sw[3];
    float scale = 1.f / (sqrtf(total) + EPSF);
    f32x4* o4 = reinterpret_cast<f32x4*>(out);
    const int nvec = N_NODES * DOUT / 4;
    for (int i = blockIdx.x * blockDim.x + threadIdx.x; i < nvec; i += gridDim.x * blockDim.x) {
        f32x4 v = o4[i];
#pragma unroll
        for (int j = 0; j < 4; ++j) v[j] *= scale;
        o4[i] = v;
    }
}

extern "C" void kernel_launch(void* const* d_in, const int* in_sizes, int n_in,
                              void* d_out, int out_size, void* d_ws, size_t ws_size,
                              hipStream_t stream) {
    const float* A   = (const float*)d_in[0];
    const float* X   = (const float*)d_in[1];
    const float* Ww  = (const float*)d_in[2];
    const float* bw  = (const float*)d_in[3];
    const float* Wfc = (const float*)d_in[4];
    const float* bfc = (const float*)d_in[5];
    float* out = (float*)d_out;

    char* ws = (char*)d_ws;
    bf16*  hT        = (bf16*)(ws);                                  // 4 MiB
    bf16*  pooled    = (bf16*)(ws + (4u << 20));                     // 4 MiB
    bf16*  WwT       = (bf16*)(ws + (8u << 20));                     // 128 KiB
    bf16*  WfcT      = (bf16*)(ws + (8u << 20) + (128u << 10));      // 256 KiB
    float* partials  = (float*)(ws + (8u << 20) + (384u << 10));     // 2 KiB

    k0_prep<<<512, 256, 0, stream>>>(Ww, Wfc, WwT, WfcT);
    k1_h<<<512, 128, 0, stream>>>(X, WwT, bw, hT);
    k2_pool<<<256, 512, 0, stream>>>(A, hT, pooled);
    k3_out<<<512, 128, 0, stream>>>(X, pooled, WfcT, bfc, out, partials);
    k4_norm<<<256, 256, 0, stream>>>(out, partials);
}